// Round 24
// baseline (2814.342 us; speedup 1.0000x reference)
//
#include <hip/hip_runtime.h>

#define NR 512
#define NI 128
#define B 32
#define T 1000
#define G2 16         // rows per load-group in the pair chain (2 floats/row/thread)
typedef float v2f __attribute__((ext_vector_type(2)));
// Locked numeric model (verified PASS rounds 13-23):
//  - input GEMM: per element single ascending-i FMA chain.
//  - z @ w_rec_masked: two 256-wide ascending-k chains (OpenBLAS K-panel
//    rebalancing: [0,256)+[256,512)), joined by one rounded add.
//    Binary z => only active rows; masked diag and zero-row pads are exact +0.
//  - elementwise: separate rounded f32 ops ((f32(decay)*v) + i_t) - z.
//  - pred: EMA over (b_out + spikes@w_out), f64, post-hoc in k_pred (loose tol).
// Round 24: load-instruction-bound (R19 8wx150 and R23 16wx75 both = 1200
// load-instrs/CU/step and within 10%) -> dwordx2 column-pairs: thread c owns
// columns {2c,2c+1} of one panel; one v2f load per row serves two fadd chains.
// 600 load-instrs/CU/step. Phase1/3 keep thread=column mapping; LDS handoff.

__device__ __forceinline__ float mul_nofma(float a, float b) {
    float r = a * b;
    asm volatile("" : "+v"(r));
    return r;
}

// LDS-only barrier: waits LDS ops, leaves global loads/stores in flight.
__device__ __forceinline__ void bar_lds() {
    asm volatile("s_waitcnt lgkmcnt(0)\n\ts_barrier" ::: "memory");
}

// ---------------- Kernel 0: masked w_rec copy + zero row into d_ws
__global__ __launch_bounds__(512) void k_prep(const float* __restrict__ w_rec,
                                              float* __restrict__ w_ws) {
    const int r = blockIdx.x, u = threadIdx.x;
    float val = 0.f;
    if (r < NR && r != u) val = w_rec[r * NR + u];
    w_ws[r * NR + u] = val;
}

// ---------------- Kernel 1: i_in = inputs @ w_in -> voltages region of d_out
template <int ROWS>
__global__ __launch_bounds__(512) void k_in_gemm(const float* __restrict__ inputs,
                                                 const float* __restrict__ w_in,
                                                 float* __restrict__ i_in) {
    const int u = threadIdx.x;
    const int r0 = blockIdx.x * ROWS;
    float acc[ROWS];
#pragma unroll
    for (int r = 0; r < ROWS; ++r) acc[r] = 0.f;
    const float* __restrict__ inp = inputs + (long)r0 * NI;
#pragma unroll 4
    for (int i = 0; i < NI; ++i) {
        float w = w_in[i * NR + u];
#pragma unroll
        for (int r = 0; r < ROWS; ++r)
            acc[r] = __builtin_fmaf(inp[r * NI + i], w, acc[r]);   // ascending i, FMA
    }
#pragma unroll
    for (int r = 0; r < ROWS; ++r)
        i_in[(long)(r0 + r) * NR + u] = acc[r];
}

// ---- pair-chain helpers: SGPR row pointers, v2f loads, static indexing
__device__ __forceinline__ void loadg2(v2f (&buf)[G2], const int* __restrict__ lp,
                                       const float* __restrict__ w_ws, int c2) {
#pragma unroll
    for (int qq = 0; qq < G2 / 4; ++qq) {
        int4 jv = *(const int4*)(lp + qq * 4);
        const float* r0 = w_ws + (__builtin_amdgcn_readfirstlane(jv.x) << 9);
        const float* r1 = w_ws + (__builtin_amdgcn_readfirstlane(jv.y) << 9);
        const float* r2 = w_ws + (__builtin_amdgcn_readfirstlane(jv.z) << 9);
        const float* r3 = w_ws + (__builtin_amdgcn_readfirstlane(jv.w) << 9);
        buf[qq * 4 + 0] = *(const v2f*)&r0[c2];
        buf[qq * 4 + 1] = *(const v2f*)&r1[c2];
        buf[qq * 4 + 2] = *(const v2f*)&r2[c2];
        buf[qq * 4 + 3] = *(const v2f*)&r3[c2];
    }
}

__device__ __forceinline__ void sumg2(const v2f (&buf)[G2], float& sx, float& sy) {
#pragma unroll
    for (int q = 0; q < G2; ++q) {
        sx = __fadd_rn(sx, buf[q].x);
        sy = __fadd_rn(sy, buf[q].y);
    }
}

// ---------------- Kernel 2: per-batch LIF scan, dwordx2 pair chains.
// 32 blocks x 512 threads; 3 LDS-only barriers/step.
// Phase 1/3: thread = column u. Phase 2: thread = (panel h, col-pair c).
__global__ __launch_bounds__(512) void k_scan(const float* __restrict__ w_ws,
                                              float* __restrict__ out) {
    const int b = blockIdx.x;
    const int tid = threadIdx.x;
    const int u = tid;                  // column (phases 1 & 3)
    const int wav = tid >> 6, lane = tid & 63;
    const int h = tid >> 8;             // panel (phase 2)
    const int c2 = (tid & 255) << 1;    // first column of the owned pair

    float* __restrict__ volt_b = out + (long)b * (T * NR);                 // also i_in (in-place)
    float* __restrict__ spk_b  = out + (long)B * T * NR + (long)b * (T * NR);

    __shared__ __align__(16) int listA[256];
    __shared__ __align__(16) int listB[256];
    __shared__ int wcnt[8];
    __shared__ __align__(16) float shs[2][NR];   // per-panel partials by column

    float v = 0.f, z = 0.f;
    const float decay = 0.951229424500714f;   // f32 rounding of the python scalar
    __syncthreads();

    for (int t = 0; t < T; ++t) {
        float ii = volt_b[t * NR + u];         // prefetch (vmcnt; survives bar_lds)

        // ---- phase 1: ballot (z == spikes[t-1]) + per-panel list build
        unsigned long long m = __ballot(z > 0.5f);
        if (lane == 0) wcnt[wav] = __popcll(m);
        bar_lds();                             // A: wcnt ready

        const int c0 = wcnt[0], c1 = wcnt[1], cc2 = wcnt[2], c3 = wcnt[3];
        const int c4 = wcnt[4], c5 = wcnt[5], c6 = wcnt[6], c7 = wcnt[7];
        const int cnt_lo = c0 + c1 + cc2 + c3;
        const int cnt_hi = c4 + c5 + c6 + c7;

        if (z > 0.5f) {
            int below = __popcll(m & ((1ull << lane) - 1ull));
            if (wav < 4) {
                int pos = (wav > 0 ? c0 : 0) + (wav > 1 ? c1 : 0) + (wav > 2 ? cc2 : 0) + below;
                listA[pos] = u;
            } else {
                int pos = (wav > 4 ? c4 : 0) + (wav > 5 ? c5 : 0) + (wav > 6 ? c6 : 0) + below;
                listB[pos] = u;
            }
        }
        // refresh stale slots -> zero row (disjoint from scatter targets)
        if (u < 256) { if (u >= cnt_lo) listA[u] = NR; }
        else         { int x = u - 256; if (x >= cnt_hi) listB[x] = NR; }
        bar_lds();                             // B: lists ready

        // ---- phase 2: own-panel pair chain, depth-2 pipelined G2-row groups
        const int* lp  = h ? listB : listA;
        const int  cnt = h ? cnt_hi : cnt_lo;
        const int  myn = (cnt + G2 - 1) / G2;
        float sx = 0.f, sy = 0.f;
        if (myn > 0) {
            v2f bA[G2], bB[G2];
            loadg2(bA, lp, w_ws, c2);
            int g = 0;
            while (true) {
                if (g + 1 < myn) loadg2(bB, lp + (g + 1) * G2, w_ws, c2);
                sumg2(bA, sx, sy);
                ++g;
                if (g == myn) break;
                if (g + 1 < myn) loadg2(bA, lp + (g + 1) * G2, w_ws, c2);
                sumg2(bB, sx, sy);
                ++g;
                if (g == myn) break;
            }
        }
        *(v2f*)&shs[h][c2] = (v2f){sx, sy};
        bar_lds();                             // C: both panels' partials ready

        // ---- phase 3: join + LIF update + stores (thread = column u)
        float rec = __fadd_rn(shs[0][u], shs[1][u]);   // panel join (one rounded add)
        float it = __fadd_rn(ii, rec);
        float m1 = mul_nofma(decay, v);
        float t2 = __fadd_rn(m1, it);
        float vn = __fsub_rn(t2, z);
        float zn = (vn > 1.0f) ? 1.0f : 0.0f;
        volt_b[t * NR + u] = vn;
        spk_b[t * NR + u]  = zn;
        v = vn; z = zn;
    }
}

// ---------------- Kernel 3: pred = EMA(b_out + spikes @ w_out), post-hoc.
__global__ __launch_bounds__(512) void k_pred(const float* __restrict__ w_out,
                                              const float* __restrict__ b_out,
                                              float* __restrict__ out) {
    const int b = blockIdx.x;
    const int tid = threadIdx.x;
    const int wav = tid >> 6, lane = tid & 63;
    const float* __restrict__ spk_b = out + (long)B * T * NR + (long)b * (T * NR);
    float* __restrict__ pred = out + 2L * B * T * NR + (long)b * T;

    __shared__ double projs[T];   // 8 KB

    double wo[8];
#pragma unroll
    for (int q = 0; q < 8; ++q) wo[q] = (double)w_out[lane + q * 64];

    for (int t = wav; t < T; t += 8) {
        double p = 0.0;
#pragma unroll
        for (int q = 0; q < 8; ++q)
            p += (double)spk_b[t * NR + lane + q * 64] * wo[q];
#pragma unroll
        for (int o = 32; o > 0; o >>= 1) p += __shfl_xor(p, o, 64);
        if (lane == 0) projs[t] = p;
    }
    __syncthreads();
    if (tid == 0) {
        const double bo = (double)b_out[0];
        double ema = 0.0;
        for (int t = 0; t < T; ++t) {
            ema = 0.8 * ema + 0.2 * (bo + projs[t]);
            pred[t] = (float)ema;
        }
    }
}

// ---------------- Fallback: verified round-13 scan (no d_ws needed)
__global__ __launch_bounds__(512) void k_scan_ref(const float* __restrict__ w_rec,
                                                  const float* __restrict__ w_out,
                                                  const float* __restrict__ b_out,
                                                  float* __restrict__ out) {
    const int b = blockIdx.x;
    const int u = threadIdx.x;
    const int wav = u >> 6, lane = u & 63;
    const int KC = 256;

    float* __restrict__ volt_b = out + (long)b * (T * NR);
    float* __restrict__ spk_b  = out + (long)B * T * NR + (long)b * (T * NR);
    float* __restrict__ pred   = out + 2L * B * T * NR;

    __shared__ __align__(16) int list[NR];
    __shared__ int wcnt[8];
    __shared__ double projp[8];

    float v = 0.f, z = 0.f;
    const float decay = 0.951229424500714f;
    const double wo = (double)w_out[u];
    const double bo = (double)b_out[0];
    double ema = 0.0;

    for (int t = 0; t < T; ++t) {
        unsigned long long m = __ballot(z > 0.5f);
        if (lane == 0) wcnt[wav] = __popcll(m);
        __syncthreads();
        int cnt = 0, base = 0;
#pragma unroll
        for (int w2 = 0; w2 < 8; ++w2) {
            int c = wcnt[w2];
            if (w2 < wav) base += c;
            cnt += c;
        }
        if (z > 0.5f) {
            int pos = base + __popcll(m & ((1ull << lane) - 1ull));
            list[pos] = u;
        }
        float ii = volt_b[t * NR + u];
        __syncthreads();

        float s1 = 0.f, s2 = 0.f;
        int k = 0;
        for (; k + 8 <= cnt; k += 8) {
            int4 ja = *(const int4*)&list[k];
            int4 jb = *(const int4*)&list[k + 4];
            int j0 = __builtin_amdgcn_readfirstlane(ja.x);
            int j1 = __builtin_amdgcn_readfirstlane(ja.y);
            int j2 = __builtin_amdgcn_readfirstlane(ja.z);
            int j3 = __builtin_amdgcn_readfirstlane(ja.w);
            int j4 = __builtin_amdgcn_readfirstlane(jb.x);
            int j5 = __builtin_amdgcn_readfirstlane(jb.y);
            int j6 = __builtin_amdgcn_readfirstlane(jb.z);
            int j7 = __builtin_amdgcn_readfirstlane(jb.w);
            float w0 = w_rec[j0 * NR + u]; if (j0 == u) w0 = 0.f;
            float w1 = w_rec[j1 * NR + u]; if (j1 == u) w1 = 0.f;
            float w2 = w_rec[j2 * NR + u]; if (j2 == u) w2 = 0.f;
            float w3 = w_rec[j3 * NR + u]; if (j3 == u) w3 = 0.f;
            float w4 = w_rec[j4 * NR + u]; if (j4 == u) w4 = 0.f;
            float w5 = w_rec[j5 * NR + u]; if (j5 == u) w5 = 0.f;
            float w6 = w_rec[j6 * NR + u]; if (j6 == u) w6 = 0.f;
            float w7 = w_rec[j7 * NR + u]; if (j7 == u) w7 = 0.f;
            if (j0 < KC) s1 = __fadd_rn(s1, w0); else s2 = __fadd_rn(s2, w0);
            if (j1 < KC) s1 = __fadd_rn(s1, w1); else s2 = __fadd_rn(s2, w1);
            if (j2 < KC) s1 = __fadd_rn(s1, w2); else s2 = __fadd_rn(s2, w2);
            if (j3 < KC) s1 = __fadd_rn(s1, w3); else s2 = __fadd_rn(s2, w3);
            if (j4 < KC) s1 = __fadd_rn(s1, w4); else s2 = __fadd_rn(s2, w4);
            if (j5 < KC) s1 = __fadd_rn(s1, w5); else s2 = __fadd_rn(s2, w5);
            if (j6 < KC) s1 = __fadd_rn(s1, w6); else s2 = __fadd_rn(s2, w6);
            if (j7 < KC) s1 = __fadd_rn(s1, w7); else s2 = __fadd_rn(s2, w7);
        }
        for (; k < cnt; ++k) {
            int j = __builtin_amdgcn_readfirstlane(list[k]);
            float w = w_rec[j * NR + u];
            if (j == u) w = 0.f;
            if (j < KC) s1 = __fadd_rn(s1, w); else s2 = __fadd_rn(s2, w);
        }
        float rec = __fadd_rn(s1, s2);

        float it = __fadd_rn(ii, rec);
        float m1 = mul_nofma(decay, v);
        float t2 = __fadd_rn(m1, it);
        float vn = __fsub_rn(t2, z);
        float zn = (vn > 1.0f) ? 1.0f : 0.0f;
        volt_b[t * NR + u] = vn;
        spk_b[t * NR + u]  = zn;

        double p = (double)zn * wo;
#pragma unroll
        for (int o = 32; o > 0; o >>= 1) p += __shfl_xor(p, o, 64);
        if (lane == 0) projp[wav] = p;
        __syncthreads();
        if (u == 0) {
            double pr = bo;
#pragma unroll
            for (int w2 = 0; w2 < 8; ++w2) pr += projp[w2];
            ema = 0.8 * ema + 0.2 * pr;
            pred[b * T + t] = (float)ema;
        }
        v = vn; z = zn;
    }
}

extern "C" void kernel_launch(void* const* d_in, const int* in_sizes, int n_in,
                              void* d_out, int out_size, void* d_ws, size_t ws_size,
                              hipStream_t stream) {
    const float* inputs = (const float*)d_in[0];
    const float* w_in   = (const float*)d_in[1];
    const float* w_rec  = (const float*)d_in[2];
    const float* w_out  = (const float*)d_in[3];
    const float* b_out  = (const float*)d_in[4];
    float* out = (float*)d_out;

    k_in_gemm<16><<<dim3(B * T / 16), dim3(512), 0, stream>>>(inputs, w_in, out);

    const size_t need = (size_t)(NR + 1) * NR * sizeof(float);
    if (ws_size >= need) {
        float* w_ws = (float*)d_ws;
        k_prep<<<dim3(NR + 1), dim3(512), 0, stream>>>(w_rec, w_ws);
        k_scan<<<dim3(B), dim3(512), 0, stream>>>(w_ws, out);
        k_pred<<<dim3(B), dim3(512), 0, stream>>>(w_out, b_out, out);
    } else {
        k_scan_ref<<<dim3(B), dim3(512), 0, stream>>>(w_rec, w_out, b_out, out);
    }
}

// Round 25
// 2215.773 us; speedup vs baseline: 1.2701x; 1.2701x over previous
//
#include <hip/hip_runtime.h>

#define NR 512
#define NI 128
#define B 32
#define T 1000
#define G 32          // load-group width; 2 buffers x 32 floats per thread
// Locked numeric model (verified PASS rounds 13-24):
//  - input GEMM: per element single ascending-i FMA chain.
//  - z @ w_rec_masked: two 256-wide ascending-k chains (OpenBLAS K-panel
//    rebalancing: [0,256)+[256,512)), joined by one rounded add.
//    Binary z => only active rows; masked diag and zero-row pads are exact +0
//    (partial sums never produce -0, so fadd(s,+0)=s exactly, any position).
//  - elementwise: separate rounded f32 ops ((f32(decay)*v) + i_t) - z.
//  - pred: EMA over (b_out + spikes@w_out), f64, post-hoc in k_pred (loose tol).
// Round 25: champion restore (= round 23). Analysis: the scan is at the
// per-CU L2-load-port roofline — cnt*512*4B ≈ 300 KB/step/block over
// ~64 B/cyc/CU = ~4800 cyc/step, matching measurement. Only 32 CUs can be
// used (32 independent sequential chains); traffic is already minimal
// (active rows only, fully coalesced). Variants with fewer waves or
// serialized chains under-utilize the port and are slower (R13,R16-R19,
// R21,R22,R24 all confirm).

__device__ __forceinline__ float mul_nofma(float a, float b) {
    float r = a * b;
    asm volatile("" : "+v"(r));
    return r;
}

// LDS-only barrier: waits LDS ops, leaves global loads/stores in flight.
__device__ __forceinline__ void bar_lds() {
    asm volatile("s_waitcnt lgkmcnt(0)\n\ts_barrier" ::: "memory");
}

// ---------------- Kernel 0: masked w_rec copy + zero row into d_ws
__global__ __launch_bounds__(512) void k_prep(const float* __restrict__ w_rec,
                                              float* __restrict__ w_ws) {
    const int r = blockIdx.x, u = threadIdx.x;
    float val = 0.f;
    if (r < NR && r != u) val = w_rec[r * NR + u];
    w_ws[r * NR + u] = val;
}

// ---------------- Kernel 1: i_in = inputs @ w_in -> voltages region of d_out
template <int ROWS>
__global__ __launch_bounds__(512) void k_in_gemm(const float* __restrict__ inputs,
                                                 const float* __restrict__ w_in,
                                                 float* __restrict__ i_in) {
    const int u = threadIdx.x;
    const int r0 = blockIdx.x * ROWS;
    float acc[ROWS];
#pragma unroll
    for (int r = 0; r < ROWS; ++r) acc[r] = 0.f;
    const float* __restrict__ inp = inputs + (long)r0 * NI;
#pragma unroll 4
    for (int i = 0; i < NI; ++i) {
        float w = w_in[i * NR + u];
#pragma unroll
        for (int r = 0; r < ROWS; ++r)
            acc[r] = __builtin_fmaf(inp[r * NI + i], w, acc[r]);   // ascending i, FMA
    }
#pragma unroll
    for (int r = 0; r < ROWS; ++r)
        i_in[(long)(r0 + r) * NR + u] = acc[r];
}

// ---- pipelined helpers: SGPR row pointers (SALU addressing), static indexing
__device__ __forceinline__ void loadg1(float (&buf)[G], const int* __restrict__ lp,
                                       const float* __restrict__ w_ws, int u) {
#pragma unroll
    for (int qq = 0; qq < G / 4; ++qq) {
        int4 jv = *(const int4*)(lp + qq * 4);
        const float* r0 = w_ws + (__builtin_amdgcn_readfirstlane(jv.x) << 9);
        const float* r1 = w_ws + (__builtin_amdgcn_readfirstlane(jv.y) << 9);
        const float* r2 = w_ws + (__builtin_amdgcn_readfirstlane(jv.z) << 9);
        const float* r3 = w_ws + (__builtin_amdgcn_readfirstlane(jv.w) << 9);
        buf[qq * 4 + 0] = r0[u];
        buf[qq * 4 + 1] = r1[u];
        buf[qq * 4 + 2] = r2[u];
        buf[qq * 4 + 3] = r3[u];
    }
}

__device__ __forceinline__ void sumg1(const float (&buf)[G], float& s) {
#pragma unroll
    for (int q = 0; q < G; ++q) s = __fadd_rn(s, buf[q]);
}

// ---------------- Kernel 2: per-batch LIF scan, panel-parallel (u,h) threads.
// 32 blocks x 1024 threads; thread (u,h) sums panel h's chain for column u.
// 3 LDS-only barriers/step; no proj/EMA in-loop.
__global__ __launch_bounds__(1024) void k_scan(const float* __restrict__ w_ws,
                                               float* __restrict__ out) {
    const int b = blockIdx.x;
    const int tid = threadIdx.x;
    const int u = tid & (NR - 1);
    const int h = tid >> 9;            // 0: panel j<256, 1: panel j>=256
    const int wav = tid >> 6;          // 0..15; waves 0..7 are h=0
    const int lane = tid & 63;

    float* __restrict__ volt_b = out + (long)b * (T * NR);                 // also i_in (in-place)
    float* __restrict__ spk_b  = out + (long)B * T * NR + (long)b * (T * NR);

    __shared__ __align__(16) int listA[256];
    __shared__ __align__(16) int listB[256];
    __shared__ int wcnt[8];
    __shared__ float shs[2][NR];

    float v = 0.f, z = 0.f;
    const float decay = 0.951229424500714f;   // f32 rounding of the python scalar
    __syncthreads();

    for (int t = 0; t < T; ++t) {
        float ii = volt_b[t * NR + u];         // prefetch (vmcnt; survives bar_lds)

        // ---- ballot: z == spikes[t-1]; h=0 waves publish counts
        unsigned long long m = __ballot(z > 0.5f);
        if (h == 0 && lane == 0) wcnt[wav] = __popcll(m);
        bar_lds();                             // A: wcnt ready

        const int c0 = wcnt[0], c1 = wcnt[1], c2 = wcnt[2], c3 = wcnt[3];
        const int c4 = wcnt[4], c5 = wcnt[5], c6 = wcnt[6], c7 = wcnt[7];
        const int cnt_lo = c0 + c1 + c2 + c3;
        const int cnt_hi = c4 + c5 + c6 + c7;

        // ---- h=0 threads build both per-panel lists (ascending u per panel)
        if (h == 0) {
            if (z > 0.5f) {
                int below = __popcll(m & ((1ull << lane) - 1ull));
                if (wav < 4) {
                    int pos = (wav > 0 ? c0 : 0) + (wav > 1 ? c1 : 0) + (wav > 2 ? c2 : 0) + below;
                    listA[pos] = u;
                } else {
                    int pos = (wav > 4 ? c4 : 0) + (wav > 5 ? c5 : 0) + (wav > 6 ? c6 : 0) + below;
                    listB[pos] = u;
                }
            }
            // refresh stale slots -> zero row (disjoint from scatter targets)
            if (u < 256) { if (u >= cnt_lo) listA[u] = NR; }
            else         { int x = u - 256; if (x >= cnt_hi) listB[x] = NR; }
        }
        bar_lds();                             // B: lists ready

        // ---- own-panel chain, depth-2 pipelined 32-wide groups (bit-exact order)
        const int* lp  = h ? listB : listA;
        const int  myn = h ? ((cnt_hi + G - 1) / G) : ((cnt_lo + G - 1) / G);
        float s = 0.f;
        if (myn > 0) {
            float bA[G], bB[G];
            loadg1(bA, lp, w_ws, u);
            int g = 0;
            while (true) {
                if (g + 1 < myn) loadg1(bB, lp + (g + 1) * G, w_ws, u);
                sumg1(bA, s);
                ++g;
                if (g == myn) break;
                if (g + 1 < myn) loadg1(bA, lp + (g + 1) * G, w_ws, u);
                sumg1(bB, s);
                ++g;
                if (g == myn) break;
            }
        }
        shs[h][u] = s;
        bar_lds();                             // C: both partials ready

        // ---- join + LIF update (reference op order, no contraction)
        float rec = __fadd_rn(shs[0][u], shs[1][u]);
        float it = __fadd_rn(ii, rec);
        float m1 = mul_nofma(decay, v);
        float t2 = __fadd_rn(m1, it);
        float vn = __fsub_rn(t2, z);
        float zn = (vn > 1.0f) ? 1.0f : 0.0f;
        if (h == 0) {
            volt_b[t * NR + u] = vn;
            spk_b[t * NR + u]  = zn;
        }
        v = vn; z = zn;                        // identical in both halves
    }
}

// ---------------- Kernel 3: pred = EMA(b_out + spikes @ w_out), post-hoc.
__global__ __launch_bounds__(512) void k_pred(const float* __restrict__ w_out,
                                              const float* __restrict__ b_out,
                                              float* __restrict__ out) {
    const int b = blockIdx.x;
    const int tid = threadIdx.x;
    const int wav = tid >> 6, lane = tid & 63;
    const float* __restrict__ spk_b = out + (long)B * T * NR + (long)b * (T * NR);
    float* __restrict__ pred = out + 2L * B * T * NR + (long)b * T;

    __shared__ double projs[T];   // 8 KB

    double wo[8];
#pragma unroll
    for (int q = 0; q < 8; ++q) wo[q] = (double)w_out[lane + q * 64];

    for (int t = wav; t < T; t += 8) {
        double p = 0.0;
#pragma unroll
        for (int q = 0; q < 8; ++q)
            p += (double)spk_b[t * NR + lane + q * 64] * wo[q];
#pragma unroll
        for (int o = 32; o > 0; o >>= 1) p += __shfl_xor(p, o, 64);
        if (lane == 0) projs[t] = p;
    }
    __syncthreads();
    if (tid == 0) {
        const double bo = (double)b_out[0];
        double ema = 0.0;
        for (int t = 0; t < T; ++t) {
            ema = 0.8 * ema + 0.2 * (bo + projs[t]);
            pred[t] = (float)ema;
        }
    }
}

// ---------------- Fallback: verified round-13 scan (no d_ws needed)
__global__ __launch_bounds__(512) void k_scan_ref(const float* __restrict__ w_rec,
                                                  const float* __restrict__ w_out,
                                                  const float* __restrict__ b_out,
                                                  float* __restrict__ out) {
    const int b = blockIdx.x;
    const int u = threadIdx.x;
    const int wav = u >> 6, lane = u & 63;
    const int KC = 256;

    float* __restrict__ volt_b = out + (long)b * (T * NR);
    float* __restrict__ spk_b  = out + (long)B * T * NR + (long)b * (T * NR);
    float* __restrict__ pred   = out + 2L * B * T * NR;

    __shared__ __align__(16) int list[NR];
    __shared__ int wcnt[8];
    __shared__ double projp[8];

    float v = 0.f, z = 0.f;
    const float decay = 0.951229424500714f;
    const double wo = (double)w_out[u];
    const double bo = (double)b_out[0];
    double ema = 0.0;

    for (int t = 0; t < T; ++t) {
        unsigned long long m = __ballot(z > 0.5f);
        if (lane == 0) wcnt[wav] = __popcll(m);
        __syncthreads();
        int cnt = 0, base = 0;
#pragma unroll
        for (int w2 = 0; w2 < 8; ++w2) {
            int c = wcnt[w2];
            if (w2 < wav) base += c;
            cnt += c;
        }
        if (z > 0.5f) {
            int pos = base + __popcll(m & ((1ull << lane) - 1ull));
            list[pos] = u;
        }
        float ii = volt_b[t * NR + u];
        __syncthreads();

        float s1 = 0.f, s2 = 0.f;
        int k = 0;
        for (; k + 8 <= cnt; k += 8) {
            int4 ja = *(const int4*)&list[k];
            int4 jb = *(const int4*)&list[k + 4];
            int j0 = __builtin_amdgcn_readfirstlane(ja.x);
            int j1 = __builtin_amdgcn_readfirstlane(ja.y);
            int j2 = __builtin_amdgcn_readfirstlane(ja.z);
            int j3 = __builtin_amdgcn_readfirstlane(ja.w);
            int j4 = __builtin_amdgcn_readfirstlane(jb.x);
            int j5 = __builtin_amdgcn_readfirstlane(jb.y);
            int j6 = __builtin_amdgcn_readfirstlane(jb.z);
            int j7 = __builtin_amdgcn_readfirstlane(jb.w);
            float w0 = w_rec[j0 * NR + u]; if (j0 == u) w0 = 0.f;
            float w1 = w_rec[j1 * NR + u]; if (j1 == u) w1 = 0.f;
            float w2 = w_rec[j2 * NR + u]; if (j2 == u) w2 = 0.f;
            float w3 = w_rec[j3 * NR + u]; if (j3 == u) w3 = 0.f;
            float w4 = w_rec[j4 * NR + u]; if (j4 == u) w4 = 0.f;
            float w5 = w_rec[j5 * NR + u]; if (j5 == u) w5 = 0.f;
            float w6 = w_rec[j6 * NR + u]; if (j6 == u) w6 = 0.f;
            float w7 = w_rec[j7 * NR + u]; if (j7 == u) w7 = 0.f;
            if (j0 < KC) s1 = __fadd_rn(s1, w0); else s2 = __fadd_rn(s2, w0);
            if (j1 < KC) s1 = __fadd_rn(s1, w1); else s2 = __fadd_rn(s2, w1);
            if (j2 < KC) s1 = __fadd_rn(s1, w2); else s2 = __fadd_rn(s2, w2);
            if (j3 < KC) s1 = __fadd_rn(s1, w3); else s2 = __fadd_rn(s2, w3);
            if (j4 < KC) s1 = __fadd_rn(s1, w4); else s2 = __fadd_rn(s2, w4);
            if (j5 < KC) s1 = __fadd_rn(s1, w5); else s2 = __fadd_rn(s2, w5);
            if (j6 < KC) s1 = __fadd_rn(s1, w6); else s2 = __fadd_rn(s2, w6);
            if (j7 < KC) s1 = __fadd_rn(s1, w7); else s2 = __fadd_rn(s2, w7);
        }
        for (; k < cnt; ++k) {
            int j = __builtin_amdgcn_readfirstlane(list[k]);
            float w = w_rec[j * NR + u];
            if (j == u) w = 0.f;
            if (j < KC) s1 = __fadd_rn(s1, w); else s2 = __fadd_rn(s2, w);
        }
        float rec = __fadd_rn(s1, s2);

        float it = __fadd_rn(ii, rec);
        float m1 = mul_nofma(decay, v);
        float t2 = __fadd_rn(m1, it);
        float vn = __fsub_rn(t2, z);
        float zn = (vn > 1.0f) ? 1.0f : 0.0f;
        volt_b[t * NR + u] = vn;
        spk_b[t * NR + u]  = zn;

        double p = (double)zn * wo;
#pragma unroll
        for (int o = 32; o > 0; o >>= 1) p += __shfl_xor(p, o, 64);
        if (lane == 0) projp[wav] = p;
        __syncthreads();
        if (u == 0) {
            double pr = bo;
#pragma unroll
            for (int w2 = 0; w2 < 8; ++w2) pr += projp[w2];
            ema = 0.8 * ema + 0.2 * pr;
            pred[b * T + t] = (float)ema;
        }
        v = vn; z = zn;
    }
}

extern "C" void kernel_launch(void* const* d_in, const int* in_sizes, int n_in,
                              void* d_out, int out_size, void* d_ws, size_t ws_size,
                              hipStream_t stream) {
    const float* inputs = (const float*)d_in[0];
    const float* w_in   = (const float*)d_in[1];
    const float* w_rec  = (const float*)d_in[2];
    const float* w_out  = (const float*)d_in[3];
    const float* b_out  = (const float*)d_in[4];
    float* out = (float*)d_out;

    k_in_gemm<16><<<dim3(B * T / 16), dim3(512), 0, stream>>>(inputs, w_in, out);

    const size_t need = (size_t)(NR + 1) * NR * sizeof(float);
    if (ws_size >= need) {
        float* w_ws = (float*)d_ws;
        k_prep<<<dim3(NR + 1), dim3(512), 0, stream>>>(w_rec, w_ws);
        k_scan<<<dim3(B), dim3(1024), 0, stream>>>(w_ws, out);
        k_pred<<<dim3(B), dim3(512), 0, stream>>>(w_out, b_out, out);
    } else {
        k_scan_ref<<<dim3(B), dim3(512), 0, stream>>>(w_rec, w_out, b_out, out);
    }
}